// Round 5
// baseline (134812.854 us; speedup 1.0000x reference)
//
#include <hip/hip_runtime.h>
#include <math.h>

// B=256 T=512 DIN=25 P=128 HID=256 3H=768 L=5 Q=0.15 EPS=1e-5
// Full-fp32. Batch in ws-tiered groups of Bg. Time axis in 8 chunks of 64.
// Per (group,layer): 9 fused rounds r=0..8: recur-role blocks (FIRST in grid,
// S=4 samples per 256-thr block) advance chunk r-1 from xwbuf[(r-1)&1];
// gemm-role blocks compute input gates for fwd chunk r / bwd chunk 7-r into
// xwbuf[r&1] on the remaining CUs. Whh streamed once per block-step for 4
// samples (4x less L2 traffic than 1 sample/block).

#define CH 64

// ---------------- Whh transpose to gate-interleaved: whhT3[l][d][k][j][3] ----
__global__ __launch_bounds__(256)
void prep_whhT3_k(const float* __restrict__ Whh0, const float* __restrict__ Whh,
                  float* __restrict__ out)
{
    int id = blockIdx.x * 256 + threadIdx.x;   // exactly 1,966,080 threads
    int u = id / 196608, rr = id % 196608;     // u = l*2+d
    int k = rr / 768, rem = rr % 768;
    int j = rem / 3, g = rem % 3;
    int l = u >> 1, d = u & 1;
    int row = g * 256 + j;                     // gate-major row in Whh
    out[id] = (l == 0) ? Whh0[(size_t)(d * 768 + row) * 256 + k]
                       : Whh[(size_t)(((l - 1) * 2 + d) * 768 + row) * 256 + k];
}

// ---------------- input projection: LN -> FC(25->128) -> GELU -> FC(128->128) --
__global__ __launch_bounds__(128)
void input_proj_k(const float* __restrict__ x, const int* __restrict__ lengths,
                  const float* __restrict__ lng, const float* __restrict__ lnb,
                  const float* __restrict__ w1, const float* __restrict__ b1v,
                  const float* __restrict__ w2, const float* __restrict__ b2v,
                  float* __restrict__ out, int b_base)
{
    const int btl = blockIdx.x;                // group-local (bl*512 + t)
    const int bl  = btl >> 9;
    const int t   = btl & 511;
    const int b   = b_base + bl;
    if (t >= lengths[b]) return;               // masked rows never read downstream
    const int tid = threadIdx.x;
    __shared__ float xs[25];
    __shared__ float xn[25];
    __shared__ float hs[128];
    if (tid < 25) xs[tid] = x[((size_t)b * 512 + t) * 25 + tid];
    __syncthreads();
    if (tid < 25) {
        float mu = 0.f;
        #pragma unroll
        for (int k = 0; k < 25; k++) mu += xs[k];
        mu *= (1.f / 25.f);
        float var = 0.f;
        #pragma unroll
        for (int k = 0; k < 25; k++) { float dd = xs[k] - mu; var += dd * dd; }
        var *= (1.f / 25.f);
        float rstd = 1.f / sqrtf(var + 1e-5f);
        xn[tid] = (xs[tid] - mu) * rstd * lng[tid] + lnb[tid];
    }
    __syncthreads();
    float a = b1v[tid];
    #pragma unroll
    for (int k = 0; k < 25; k++) a = fmaf(xn[k], w1[k * 128 + tid], a);
    float ge = 0.5f * a * (1.f + erff(a * 0.70710678118654752440f));
    hs[tid] = ge;
    __syncthreads();
    float o = b2v[tid];
    #pragma unroll 8
    for (int k = 0; k < 128; k++) o = fmaf(hs[k], w2[k * 128 + tid], o);
    out[(size_t)btl * 128 + tid] = o;
}

// ---------------- fused round: recur(chunk r-1) FIRST, then gemm(chunk r) ----
// blocks [0, NR): recur role. 4 samples + one dir per block, 256 thr; thread
//   tid owns hidden unit j=tid (gate cols j, 256+j, 512+j); Whh streamed once
//   per step serves all 4 samples; h double-buffered in LDS, 1 sync/step.
// blocks [NR, NR+NG): GEMM role. 64Mx128N tile, A = H_l rows (stride K),
//   B = raw Wih slice [2][768][K] staged via LDS. Out: xw_w[(d*Bg+s)*64+row][768].
__global__ __launch_bounds__(256)
void round_k(const float* __restrict__ A, int K,
             const float* __restrict__ W,      // raw Wih layer slice [2][768][K]
             const float* __restrict__ bi,     // [2][768]
             const int* __restrict__ lengths, int b_base, int Bg,
             float* __restrict__ xw_w, int lo_fw, int lo_bw,
             const float* __restrict__ xw_r, int lo_fr, int lo_br,
             const float* __restrict__ whhT3,  // layer slice [2][256][256][3]
             const float* __restrict__ bhh,    // [2][768]
             float* __restrict__ Y,            // bout [Bg*512][512]
             float* __restrict__ hstate,       // [2*Bg][256] sample-major
             int NR, int first)
{
    __shared__ float As[8][68];        // gemm: [k][m]
    __shared__ float Bs[8][132];       // gemm: [k][n]
    __shared__ float h_s[2][256][4];   // recur: double-buffered h, [k][sample]

    const int tid = threadIdx.x;

    if ((int)blockIdx.x < NR) {
        // ================= recur role =================
        const int nT   = Bg >> 2;                  // tiles per dir
        const int d    = ((int)blockIdx.x >= nT) ? 1 : 0;
        const int tile = (int)blockIdx.x - d * nT;
        const int b0   = tile * 4;                 // group-local first sample
        const int lo   = d ? lo_br : lo_fr;

        int nst[4];
        int nmax = 0;
        #pragma unroll
        for (int s = 0; s < 4; s++) {
            int L = lengths[b_base + b0 + s];
            int n = min(lo + CH, L) - lo;
            nst[s] = (n < 0) ? 0 : n;
            nmax = max(nmax, nst[s]);
        }
        if (!first && nmax <= 0) return;           // hstate already valid

        float* hg = hstate + (size_t)(d * Bg + b0) * 256;
        #pragma unroll
        for (int s = 0; s < 4; s++)
            h_s[0][tid][s] = first ? 0.f : hg[s * 256 + tid];
        __syncthreads();

        const float* W3  = whhT3 + (size_t)d * 196608;   // [256][256][3]
        const float* xwd = xw_r + (size_t)(d * Bg + b0) * (64 * 768);
        const float bhr = bhh[d * 768 + tid];
        const float bhz = bhh[d * 768 + 256 + tid];
        const float bhn = bhh[d * 768 + 512 + tid];

        int par = 0;
        for (int st = 0; st < nmax; st++) {
            float ar[4], az[4], an[4];
            #pragma unroll
            for (int s = 0; s < 4; s++) { ar[s] = bhr; az[s] = bhz; an[s] = bhn; }
            const float* wp = W3 + tid * 3;
            #pragma unroll 4
            for (int k = 0; k < 256; k++) {
                float4 h4 = *(const float4*)&h_s[par][k][0];  // broadcast
                float wr = wp[0], wz = wp[1], wn = wp[2];     // coalesced 12B
                wp += 768;
                ar[0] = fmaf(h4.x, wr, ar[0]); ar[1] = fmaf(h4.y, wr, ar[1]);
                ar[2] = fmaf(h4.z, wr, ar[2]); ar[3] = fmaf(h4.w, wr, ar[3]);
                az[0] = fmaf(h4.x, wz, az[0]); az[1] = fmaf(h4.y, wz, az[1]);
                az[2] = fmaf(h4.z, wz, az[2]); az[3] = fmaf(h4.w, wz, az[3]);
                an[0] = fmaf(h4.x, wn, an[0]); an[1] = fmaf(h4.y, wn, an[1]);
                an[2] = fmaf(h4.z, wn, an[2]); an[3] = fmaf(h4.w, wn, an[3]);
            }
            float4 hv4 = *(const float4*)&h_s[par][tid][0];
            float hold[4] = {hv4.x, hv4.y, hv4.z, hv4.w};
            float hnew[4];
            #pragma unroll
            for (int s = 0; s < 4; s++) {
                float hn = hold[s];
                if (st < nst[s]) {                 // block-uniform branch
                    int p = d ? (lo + nst[s] - 1 - st) : (lo + st);
                    const float* xr = xwd + ((size_t)s * 64 + (p - lo)) * 768;
                    float r = 1.f / (1.f + expf(-(xr[tid] + ar[s])));
                    float z = 1.f / (1.f + expf(-(xr[256 + tid] + az[s])));
                    float n = tanhf(xr[512 + tid] + r * an[s]);
                    hn = (1.f - z) * n + z * hold[s];
                    Y[((size_t)((b0 + s) * 512 + p)) * 512 + d * 256 + tid] = hn;
                }
                hnew[s] = hn;
            }
            *(float4*)&h_s[par ^ 1][tid][0] =
                make_float4(hnew[0], hnew[1], hnew[2], hnew[3]);
            par ^= 1;
            __syncthreads();
        }
        #pragma unroll
        for (int s = 0; s < 4; s++) hg[s * 256 + tid] = h_s[par][tid][s];
    } else {
        // ================= GEMM role =================
        const int gid  = blockIdx.x - NR;
        const int nt   = gid % 6;
        const int rest = gid / 6;
        const int d    = (rest >= Bg) ? 1 : 0;
        const int s    = rest - d * Bg;
        const int lo   = d ? lo_bw : lo_fw;
        if (lengths[b_base + s] <= lo) return;   // chunk fully masked for sample

        float acc[4][8] = {};
        const int tm = tid >> 4;                 // 0..15 -> rows tm*4..+3
        const int tn = tid & 15;                 // cols {tn*4..+3, 64+tn*4..+3}
        const int arr = tid >> 2, ak = (tid & 3) * 2;
        const int bn = tid >> 1, bk = (tid & 1) * 4;

        const float* Ap = A + (size_t)(s * 512 + lo + arr) * K + ak;
        const float* Wp = W + ((size_t)d * 768 + nt * 128 + bn) * K + bk;

        for (int k0 = 0; k0 < K; k0 += 8) {
            float2 av = *(const float2*)(Ap + k0);
            float4 bv = *(const float4*)(Wp + k0);
            __syncthreads();
            As[ak][arr] = av.x; As[ak + 1][arr] = av.y;
            Bs[bk + 0][bn] = bv.x; Bs[bk + 1][bn] = bv.y;
            Bs[bk + 2][bn] = bv.z; Bs[bk + 3][bn] = bv.w;
            __syncthreads();
            #pragma unroll
            for (int kk = 0; kk < 8; kk++) {
                float4 a4 = *(const float4*)&As[kk][tm * 4];
                float4 b0v = *(const float4*)&Bs[kk][tn * 4];
                float4 b1v = *(const float4*)&Bs[kk][64 + tn * 4];
                float ar4[4] = {a4.x, a4.y, a4.z, a4.w};
                float br[8] = {b0v.x, b0v.y, b0v.z, b0v.w,
                               b1v.x, b1v.y, b1v.z, b1v.w};
                #pragma unroll
                for (int i = 0; i < 4; i++)
                    #pragma unroll
                    for (int j = 0; j < 8; j++)
                        acc[i][j] = fmaf(ar4[i], br[j], acc[i][j]);
            }
        }
        const int cb = d * 768 + nt * 128;
        float bv0[4], bv1[4];
        #pragma unroll
        for (int j = 0; j < 4; j++) {
            bv0[j] = bi[cb + tn * 4 + j];
            bv1[j] = bi[cb + 64 + tn * 4 + j];
        }
        #pragma unroll
        for (int i = 0; i < 4; i++) {
            const int row = tm * 4 + i;
            float* o = xw_w + (size_t)((d * Bg + s) * 64 + row) * 768 + nt * 128 + tn * 4;
            float4 c0 = make_float4(acc[i][0] + bv0[0], acc[i][1] + bv0[1],
                                    acc[i][2] + bv0[2], acc[i][3] + bv0[3]);
            float4 c1 = make_float4(acc[i][4] + bv1[0], acc[i][5] + bv1[1],
                                    acc[i][6] + bv1[2], acc[i][7] + bv1[3]);
            *(float4*)(o)      = c0;
            *(float4*)(o + 64) = c1;
        }
    }
}

// ---------------- top-Q pooling + classifier head ----------------
__global__ __launch_bounds__(256)
void pool_k(const float* __restrict__ H, const int* __restrict__ lengths,
            const float* __restrict__ Wc, const float* __restrict__ bcp,
            float* __restrict__ out, int b_base)
{
    const int bl = blockIdx.x;
    const int b  = b_base + bl;
    const int tid = threadIdx.x;
    __shared__ float sc[512];
    __shared__ int   sel[128];
    __shared__ int   nsel;
    __shared__ float red[256];
    const int len = lengths[b];
    const int k = max(1, (int)ceilf((float)len * 0.15f));   // jnp fp32 semantics
    if (tid == 0) nsel = 0;
    for (int t = tid; t < 512; t += 256) {
        float s;
        if (t < len) {
            const float* row = H + ((size_t)bl * 512 + t) * 512;
            float acc = 0.f;
            for (int j = 0; j < 512; j++) acc = fmaf(row[j], row[j], acc);
            s = sqrtf(acc);
        } else s = -1e9f;
        sc[t] = s;
    }
    __syncthreads();
    // stable top-k: include t iff (#strictly greater) + (#equal, smaller idx) < k
    for (int t = tid; t < 512; t += 256) {
        if (t < len) {
            const float s = sc[t];
            int cnt = 0;
            for (int u = 0; u < 512; u++) {
                float su = sc[u];
                cnt += (su > s || (su == s && u < t)) ? 1 : 0;
            }
            if (cnt < k) { int p = atomicAdd(&nsel, 1); sel[p] = t; }
        }
    }
    __syncthreads();
    const int ns = nsel;                       // == k
    float part = 0.f;
    for (int j = tid; j < 512; j += 256) {
        float acc = 0.f;
        for (int i = 0; i < ns; i++)
            acc += H[((size_t)bl * 512 + sel[i]) * 512 + j];
        part += (acc / (float)k) * Wc[j];
    }
    red[tid] = part;
    __syncthreads();
    for (int s2 = 128; s2 > 0; s2 >>= 1) {
        if (tid < s2) red[tid] += red[tid + s2];
        __syncthreads();
    }
    if (tid == 0) out[b] = red[0] + bcp[0];
}

// ---------------- host ----------------
static inline size_t alup(size_t x) { return (x + 255) & ~255ull; }

static size_t tier_bytes(int Bg)
{
    return 2 * alup((size_t)Bg * 512 * 512 * 4)        // H ping-pong
         + 2 * alup((size_t)Bg * 2 * 64 * 768 * 4)     // xw ping-pong
         + alup(1966080ull * 4)                        // whhT3
         + alup((size_t)Bg * 2 * 256 * 4);             // hstate
}

extern "C" void kernel_launch(void* const* d_in, const int* in_sizes, int n_in,
                              void* d_out, int out_size, void* d_ws, size_t ws_size,
                              hipStream_t stream)
{
    const float* x    = (const float*)d_in[0];
    const int*   len  = (const int*)  d_in[1];
    const float* ln_g = (const float*)d_in[2];
    const float* ln_b = (const float*)d_in[3];
    const float* w1   = (const float*)d_in[4];
    const float* b1   = (const float*)d_in[5];
    const float* w2   = (const float*)d_in[6];
    const float* b2   = (const float*)d_in[7];
    const float* Wih0 = (const float*)d_in[8];
    const float* Whh0 = (const float*)d_in[9];
    const float* bih0 = (const float*)d_in[10];
    const float* bhh0 = (const float*)d_in[11];
    const float* Wih  = (const float*)d_in[12];
    const float* Whh  = (const float*)d_in[13];
    const float* bih  = (const float*)d_in[14];
    const float* bhh  = (const float*)d_in[15];
    const float* Wc   = (const float*)d_in[16];
    const float* bc   = (const float*)d_in[17];
    float* out = (float*)d_out;

    int Bg = 0;
    const int tiers[5] = {128, 64, 32, 16, 8};
    for (int i = 0; i < 5; i++)
        if (ws_size >= tier_bytes(tiers[i])) { Bg = tiers[i]; break; }
    if (Bg == 0) return;

    char* ws = (char*)d_ws;
    size_t off = 0;
    auto alloc = [&](size_t bytes) { size_t o = off; off += alup(bytes); return o; };
    float* h0    = (float*)(ws + alloc((size_t)Bg * 512 * 512 * 4));
    float* h1    = (float*)(ws + alloc((size_t)Bg * 512 * 512 * 4));
    float* xwA   = (float*)(ws + alloc((size_t)Bg * 2 * 64 * 768 * 4));
    float* xwB   = (float*)(ws + alloc((size_t)Bg * 2 * 64 * 768 * 4));
    float* whhT3 = (float*)(ws + alloc(1966080ull * 4));
    float* hst   = (float*)(ws + alloc((size_t)Bg * 2 * 256 * 4));
    float* xwbuf[2] = {xwA, xwB};

    prep_whhT3_k<<<7680, 256, 0, stream>>>(Whh0, Whh, whhT3);

    for (int g = 0; g < 256; g += Bg) {
        input_proj_k<<<Bg * 512, 128, 0, stream>>>(x, len, ln_g, ln_b, w1, b1,
                                                   w2, b2, h0, g);
        float* bin = h0;
        float* bout = h1;
        for (int l = 0; l < 5; l++) {
            const int K = (l == 0) ? 128 : 512;
            const float* Wl  = (l == 0) ? Wih0 : (Wih + (size_t)(l - 1) * 2 * 768 * 512);
            const float* bil = (l == 0) ? bih0 : (bih + (size_t)(l - 1) * 1536);
            const float* whl = whhT3 + (size_t)l * 393216;
            const float* bhl = (l == 0) ? bhh0 : (bhh + (size_t)(l - 1) * 1536);
            for (int r = 0; r <= 8; r++) {
                const int NR = (r > 0) ? 2 * (Bg / 4) : 0;
                const int NG = (r < 8) ? 12 * Bg : 0;
                round_k<<<NR + NG, 256, 0, stream>>>(
                    bin, K, Wl, bil, len, g, Bg,
                    xwbuf[r & 1], r * 64, (7 - r) * 64,
                    xwbuf[(r & 1) ^ 1], (r - 1) * 64, (8 - r) * 64,
                    whl, bhl, bout, hst, NR, (r == 1) ? 1 : 0);
            }
            float* tmp = bin; bin = bout; bout = tmp;
        }
        pool_k<<<Bg, 256, 0, stream>>>(bin, len, Wc, bc, out, g);
    }
}

// Round 6
// 96567.480 us; speedup vs baseline: 1.3960x; 1.3960x over previous
//
#include <hip/hip_runtime.h>
#include <math.h>

// B=256 T=512 DIN=25 P=128 HID=256 3H=768 L=5 Q=0.15 EPS=1e-5
// Full-fp32. ws-tiered batch groups (ws>=391MB observed => Bg=128, 2 groups).
// Length-sorted sample permutation (stable) so groups are length-homogeneous.
// Per (group,layer): 9 rounds r=0..8: gemm_k computes input gates for fwd
// chunk r / bwd chunk 7-r into xwbuf[r&1]; recur_k advances chunk r-1 (both
// dirs, 4 samples per block, gate-interleaved Whh, one sync per step).
// Split kernels (vs fused) so each gets its own register allocation — the
// fused version spilled GEMM accumulators (VGPR 36) and ran 2x slower.

#define CH 64

// ---------------- stable ascending length sort: perm[rank] = sample ----------
__global__ __launch_bounds__(256)
void sort_k(const int* __restrict__ len, int* __restrict__ perm)
{
    const int i = threadIdx.x;
    const int li = len[i];
    int r = 0;
    for (int j = 0; j < 256; j++) {
        int lj = len[j];
        r += (lj < li || (lj == li && j < i)) ? 1 : 0;
    }
    perm[r] = i;
}

// ---------------- Whh transpose to gate-interleaved: whhT3[l][d][k][j][3] ----
__global__ __launch_bounds__(256)
void prep_whhT3_k(const float* __restrict__ Whh0, const float* __restrict__ Whh,
                  float* __restrict__ out)
{
    int id = blockIdx.x * 256 + threadIdx.x;   // exactly 1,966,080 threads
    int u = id / 196608, rr = id % 196608;     // u = l*2+d
    int k = rr / 768, rem = rr % 768;
    int j = rem / 3, g = rem % 3;
    int l = u >> 1, d = u & 1;
    int row = g * 256 + j;                     // gate-major row in Whh
    out[id] = (l == 0) ? Whh0[(size_t)(d * 768 + row) * 256 + k]
                       : Whh[(size_t)(((l - 1) * 2 + d) * 768 + row) * 256 + k];
}

// ---------------- input projection: LN -> FC(25->128) -> GELU -> FC(128->128) --
__global__ __launch_bounds__(128)
void input_proj_k(const float* __restrict__ x, const int* __restrict__ lengths,
                  const int* __restrict__ perm,
                  const float* __restrict__ lng, const float* __restrict__ lnb,
                  const float* __restrict__ w1, const float* __restrict__ b1v,
                  const float* __restrict__ w2, const float* __restrict__ b2v,
                  float* __restrict__ out, int g0)
{
    const int btl = blockIdx.x;                // group-local (sl*512 + t)
    const int sl  = btl >> 9;
    const int t   = btl & 511;
    const int b   = perm[g0 + sl];
    if (t >= lengths[b]) return;               // masked rows never read downstream
    const int tid = threadIdx.x;
    __shared__ float xs[25];
    __shared__ float xn[25];
    __shared__ float hs[128];
    if (tid < 25) xs[tid] = x[((size_t)b * 512 + t) * 25 + tid];
    __syncthreads();
    if (tid < 25) {
        float mu = 0.f;
        #pragma unroll
        for (int k = 0; k < 25; k++) mu += xs[k];
        mu *= (1.f / 25.f);
        float var = 0.f;
        #pragma unroll
        for (int k = 0; k < 25; k++) { float dd = xs[k] - mu; var += dd * dd; }
        var *= (1.f / 25.f);
        float rstd = 1.f / sqrtf(var + 1e-5f);
        xn[tid] = (xs[tid] - mu) * rstd * lng[tid] + lnb[tid];
    }
    __syncthreads();
    float a = b1v[tid];
    #pragma unroll
    for (int k = 0; k < 25; k++) a = fmaf(xn[k], w1[k * 128 + tid], a);
    float ge = 0.5f * a * (1.f + erff(a * 0.70710678118654752440f));
    hs[tid] = ge;
    __syncthreads();
    float o = b2v[tid];
    #pragma unroll 8
    for (int k = 0; k < 128; k++) o = fmaf(hs[k], w2[k * 128 + tid], o);
    out[(size_t)btl * 128 + tid] = o;
}

// ---------------- per-chunk input-gate GEMM ----------------
// grid (6, 2*Bg): 64Mx128N tile. y < Bg -> dir0 (fwd chunk lo_f), else dir1
// (bwd chunk lo_b). A rows are group-local slots; length guard via perm.
__global__ __launch_bounds__(256, 2)
void gemm_k(const float* __restrict__ A, int K,
            const float* __restrict__ W,       // raw Wih layer slice [2][768][K]
            const float* __restrict__ bi,      // [2][768]
            const int* __restrict__ lengths, const int* __restrict__ perm,
            int g0, int Bg,
            float* __restrict__ C, int lo_f, int lo_b)
{
    const int nt  = blockIdx.x;                // 0..5
    const int my  = blockIdx.y;
    const int dir = (my >= Bg) ? 1 : 0;
    const int s   = my - dir * Bg;             // group-local slot
    const int lo  = dir ? lo_b : lo_f;
    if (lengths[perm[g0 + s]] <= lo) return;   // chunk fully masked
    const int tid = threadIdx.x;

    __shared__ float As[8][68];                // [k][m]
    __shared__ float Bs[8][132];               // [k][n]

    float acc[4][8] = {};
    const int tm = tid >> 4;                   // rows tm*4..+3
    const int tn = tid & 15;                   // cols {tn*4..+3, 64+tn*4..+3}
    const int arr = tid >> 2, ak = (tid & 3) * 2;
    const int bn = tid >> 1, bk = (tid & 1) * 4;

    const float* Ap = A + (size_t)(s * 512 + lo + arr) * K + ak;
    const float* Wp = W + ((size_t)dir * 768 + nt * 128 + bn) * K + bk;

    for (int k0 = 0; k0 < K; k0 += 8) {
        float2 av = *(const float2*)(Ap + k0);
        float4 bv = *(const float4*)(Wp + k0);
        __syncthreads();
        As[ak][arr] = av.x; As[ak + 1][arr] = av.y;
        Bs[bk + 0][bn] = bv.x; Bs[bk + 1][bn] = bv.y;
        Bs[bk + 2][bn] = bv.z; Bs[bk + 3][bn] = bv.w;
        __syncthreads();
        #pragma unroll
        for (int kk = 0; kk < 8; kk++) {
            float4 a4 = *(const float4*)&As[kk][tm * 4];
            float4 b0v = *(const float4*)&Bs[kk][tn * 4];
            float4 b1v = *(const float4*)&Bs[kk][64 + tn * 4];
            float ar4[4] = {a4.x, a4.y, a4.z, a4.w};
            float br[8] = {b0v.x, b0v.y, b0v.z, b0v.w,
                           b1v.x, b1v.y, b1v.z, b1v.w};
            #pragma unroll
            for (int i = 0; i < 4; i++)
                #pragma unroll
                for (int j = 0; j < 8; j++)
                    acc[i][j] = fmaf(ar4[i], br[j], acc[i][j]);
        }
    }
    const int cb = dir * 768 + nt * 128;
    float bv0[4], bv1[4];
    #pragma unroll
    for (int j = 0; j < 4; j++) {
        bv0[j] = bi[cb + tn * 4 + j];
        bv1[j] = bi[cb + 64 + tn * 4 + j];
    }
    #pragma unroll
    for (int i = 0; i < 4; i++) {
        const int row = tm * 4 + i;
        float* o = C + (size_t)((dir * Bg + s) * 64 + row) * 768 + nt * 128 + tn * 4;
        float4 c0 = make_float4(acc[i][0] + bv0[0], acc[i][1] + bv0[1],
                                acc[i][2] + bv0[2], acc[i][3] + bv0[3]);
        float4 c1 = make_float4(acc[i][4] + bv1[0], acc[i][5] + bv1[1],
                                acc[i][6] + bv1[2], acc[i][7] + bv1[3]);
        *(float4*)(o)      = c0;
        *(float4*)(o + 64) = c1;
    }
}

// ---------------- chunked masked bidirectional GRU recurrence ----------------
// grid 2*(Bg/4) blocks x 256 thr: 4 samples + one dir per block. Thread tid
// owns hidden unit j=tid (gate cols j, 256+j, 512+j) with FULL K loop —
// no partial-reduce exchange, ONE sync per step. Whh gate-interleaved
// [k][j][3] so the 256-thread read per k is one contiguous 3KB line.
__global__ __launch_bounds__(256, 2)
void recur_k(const float* __restrict__ xw_r, const float* __restrict__ whhT3,
             const float* __restrict__ bhh, const int* __restrict__ lengths,
             const int* __restrict__ perm, int g0, int Bg,
             float* __restrict__ Y, float* __restrict__ hstate,
             int lo_f, int lo_b, int first)
{
    const int nT   = Bg >> 2;
    const int d    = ((int)blockIdx.x >= nT) ? 1 : 0;
    const int tile = (int)blockIdx.x - d * nT;
    const int b0   = tile * 4;
    const int tid  = threadIdx.x;
    const int lo   = d ? lo_b : lo_f;

    __shared__ float h_s[2][256][4];

    int nst[4];
    int nmax = 0;
    #pragma unroll
    for (int s = 0; s < 4; s++) {
        int L = lengths[perm[g0 + b0 + s]];
        int n = min(lo + CH, L) - lo;
        nst[s] = (n < 0) ? 0 : n;
        nmax = max(nmax, nst[s]);
    }
    if (!first && nmax <= 0) return;           // hstate already valid

    float* hg = hstate + (size_t)(d * Bg + b0) * 256;
    #pragma unroll
    for (int s = 0; s < 4; s++)
        h_s[0][tid][s] = first ? 0.f : hg[s * 256 + tid];
    __syncthreads();

    const float* W3  = whhT3 + (size_t)d * 196608;   // [256][256][3]
    const float* xwd = xw_r + (size_t)(d * Bg + b0) * (64 * 768);
    const float bhr = bhh[d * 768 + tid];
    const float bhz = bhh[d * 768 + 256 + tid];
    const float bhn = bhh[d * 768 + 512 + tid];

    int par = 0;
    for (int st = 0; st < nmax; st++) {
        float ar[4], az[4], an[4];
        #pragma unroll
        for (int s = 0; s < 4; s++) { ar[s] = bhr; az[s] = bhz; an[s] = bhn; }
        const float* wp = W3 + tid * 3;
        #pragma unroll 8
        for (int k = 0; k < 256; k++) {
            float4 h4 = *(const float4*)&h_s[par][k][0];  // LDS broadcast
            float wr = wp[0], wz = wp[1], wn = wp[2];     // coalesced 12B
            wp += 768;
            ar[0] = fmaf(h4.x, wr, ar[0]); ar[1] = fmaf(h4.y, wr, ar[1]);
            ar[2] = fmaf(h4.z, wr, ar[2]); ar[3] = fmaf(h4.w, wr, ar[3]);
            az[0] = fmaf(h4.x, wz, az[0]); az[1] = fmaf(h4.y, wz, az[1]);
            az[2] = fmaf(h4.z, wz, az[2]); az[3] = fmaf(h4.w, wz, az[3]);
            an[0] = fmaf(h4.x, wn, an[0]); an[1] = fmaf(h4.y, wn, an[1]);
            an[2] = fmaf(h4.z, wn, an[2]); an[3] = fmaf(h4.w, wn, an[3]);
        }
        float4 hv4 = *(const float4*)&h_s[par][tid][0];
        float hold[4] = {hv4.x, hv4.y, hv4.z, hv4.w};
        float hnew[4];
        #pragma unroll
        for (int s = 0; s < 4; s++) {
            float hn = hold[s];
            if (st < nst[s]) {
                int p = d ? (lo + nst[s] - 1 - st) : (lo + st);
                const float* xr = xwd + ((size_t)s * 64 + (p - lo)) * 768;
                float r = 1.f / (1.f + expf(-(xr[tid] + ar[s])));
                float z = 1.f / (1.f + expf(-(xr[256 + tid] + az[s])));
                float n = tanhf(xr[512 + tid] + r * an[s]);
                hn = (1.f - z) * n + z * hold[s];
                Y[((size_t)((b0 + s) * 512 + p)) * 512 + d * 256 + tid] = hn;
            }
            hnew[s] = hn;
        }
        *(float4*)&h_s[par ^ 1][tid][0] =
            make_float4(hnew[0], hnew[1], hnew[2], hnew[3]);
        par ^= 1;
        __syncthreads();
    }
    #pragma unroll
    for (int s = 0; s < 4; s++) hg[s * 256 + tid] = h_s[par][tid][s];
}

// ---------------- top-Q pooling + classifier head ----------------
__global__ __launch_bounds__(256)
void pool_k(const float* __restrict__ H, const int* __restrict__ lengths,
            const int* __restrict__ perm,
            const float* __restrict__ Wc, const float* __restrict__ bcp,
            float* __restrict__ out, int g0)
{
    const int bl = blockIdx.x;                 // group-local
    const int b  = perm[g0 + bl];
    const int tid = threadIdx.x;
    __shared__ float sc[512];
    __shared__ int   sel[128];
    __shared__ int   nsel;
    __shared__ float red[256];
    const int len = lengths[b];
    const int k = max(1, (int)ceilf((float)len * 0.15f));   // jnp fp32 semantics
    if (tid == 0) nsel = 0;
    for (int t = tid; t < 512; t += 256) {
        float s;
        if (t < len) {
            const float* row = H + ((size_t)bl * 512 + t) * 512;
            float acc = 0.f;
            for (int j = 0; j < 512; j++) acc = fmaf(row[j], row[j], acc);
            s = sqrtf(acc);
        } else s = -1e9f;
        sc[t] = s;
    }
    __syncthreads();
    // stable top-k: include t iff (#strictly greater) + (#equal, smaller idx) < k
    for (int t = tid; t < 512; t += 256) {
        if (t < len) {
            const float s = sc[t];
            int cnt = 0;
            for (int u = 0; u < 512; u++) {
                float su = sc[u];
                cnt += (su > s || (su == s && u < t)) ? 1 : 0;
            }
            if (cnt < k) { int p = atomicAdd(&nsel, 1); sel[p] = t; }
        }
    }
    __syncthreads();
    const int ns = nsel;                       // == k
    float part = 0.f;
    for (int j = tid; j < 512; j += 256) {
        float acc = 0.f;
        for (int i = 0; i < ns; i++)
            acc += H[((size_t)bl * 512 + sel[i]) * 512 + j];
        part += (acc / (float)k) * Wc[j];
    }
    red[tid] = part;
    __syncthreads();
    for (int s2 = 128; s2 > 0; s2 >>= 1) {
        if (tid < s2) red[tid] += red[tid + s2];
        __syncthreads();
    }
    if (tid == 0) out[b] = red[0] + bcp[0];
}

// ---------------- host ----------------
static inline size_t alup(size_t x) { return (x + 255) & ~255ull; }

static size_t tier_bytes(int Bg)
{
    return 2 * alup((size_t)Bg * 512 * 512 * 4)        // H ping-pong
         + 2 * alup((size_t)Bg * 2 * 64 * 768 * 4)     // xw ping-pong
         + alup(1966080ull * 4)                        // whhT3
         + alup((size_t)Bg * 2 * 256 * 4)              // hstate
         + alup(256 * 4);                              // perm
}

extern "C" void kernel_launch(void* const* d_in, const int* in_sizes, int n_in,
                              void* d_out, int out_size, void* d_ws, size_t ws_size,
                              hipStream_t stream)
{
    const float* x    = (const float*)d_in[0];
    const int*   len  = (const int*)  d_in[1];
    const float* ln_g = (const float*)d_in[2];
    const float* ln_b = (const float*)d_in[3];
    const float* w1   = (const float*)d_in[4];
    const float* b1   = (const float*)d_in[5];
    const float* w2   = (const float*)d_in[6];
    const float* b2   = (const float*)d_in[7];
    const float* Wih0 = (const float*)d_in[8];
    const float* Whh0 = (const float*)d_in[9];
    const float* bih0 = (const float*)d_in[10];
    const float* bhh0 = (const float*)d_in[11];
    const float* Wih  = (const float*)d_in[12];
    const float* Whh  = (const float*)d_in[13];
    const float* bih  = (const float*)d_in[14];
    const float* bhh  = (const float*)d_in[15];
    const float* Wc   = (const float*)d_in[16];
    const float* bc   = (const float*)d_in[17];
    float* out = (float*)d_out;

    int Bg = 0;
    const int tiers[5] = {128, 64, 32, 16, 8};
    for (int i = 0; i < 5; i++)
        if (ws_size >= tier_bytes(tiers[i])) { Bg = tiers[i]; break; }
    if (Bg == 0) return;

    char* ws = (char*)d_ws;
    size_t off = 0;
    auto alloc = [&](size_t bytes) { size_t o = off; off += alup(bytes); return o; };
    float* h0    = (float*)(ws + alloc((size_t)Bg * 512 * 512 * 4));
    float* h1    = (float*)(ws + alloc((size_t)Bg * 512 * 512 * 4));
    float* xwA   = (float*)(ws + alloc((size_t)Bg * 2 * 64 * 768 * 4));
    float* xwB   = (float*)(ws + alloc((size_t)Bg * 2 * 64 * 768 * 4));
    float* whhT3 = (float*)(ws + alloc(1966080ull * 4));
    float* hst   = (float*)(ws + alloc((size_t)Bg * 2 * 256 * 4));
    int*   perm  = (int*)  (ws + alloc(256 * 4));
    float* xwbuf[2] = {xwA, xwB};

    sort_k<<<1, 256, 0, stream>>>(len, perm);
    prep_whhT3_k<<<7680, 256, 0, stream>>>(Whh0, Whh, whhT3);

    for (int g0 = 0; g0 < 256; g0 += Bg) {
        input_proj_k<<<Bg * 512, 128, 0, stream>>>(x, len, perm, ln_g, ln_b,
                                                   w1, b1, w2, b2, h0, g0);
        float* bin = h0;
        float* bout = h1;
        for (int l = 0; l < 5; l++) {
            const int K = (l == 0) ? 128 : 512;
            const float* Wl  = (l == 0) ? Wih0 : (Wih + (size_t)(l - 1) * 2 * 768 * 512);
            const float* bil = (l == 0) ? bih0 : (bih + (size_t)(l - 1) * 1536);
            const float* whl = whhT3 + (size_t)l * 393216;
            const float* bhl = (l == 0) ? bhh0 : (bhh + (size_t)(l - 1) * 1536);
            for (int r = 0; r <= 8; r++) {
                if (r < 8)
                    gemm_k<<<dim3(6, 2 * Bg), 256, 0, stream>>>(
                        bin, K, Wl, bil, len, perm, g0, Bg,
                        xwbuf[r & 1], r * 64, (7 - r) * 64);
                if (r > 0)
                    recur_k<<<2 * (Bg / 4), 256, 0, stream>>>(
                        xwbuf[(r - 1) & 1], whl, bhl, len, perm, g0, Bg,
                        bout, hst, (r - 1) * 64, (8 - r) * 64, (r == 1) ? 1 : 0);
            }
            float* tmp = bin; bin = bout; bout = tmp;
        }
        pool_k<<<Bg, 256, 0, stream>>>(bin, len, perm, Wc, bc, out, g0);
    }
}